// Round 8
// baseline (46.485 us; speedup 1.0000x reference)
//
#include <hip/hip_runtime.h>

typedef unsigned short u16;
typedef unsigned int u32;
typedef _Float16 f16x8 __attribute__((ext_vector_type(8)));
typedef float f32x4 __attribute__((ext_vector_type(4)));

#define B_ 8
#define C_ 64
#define H_ 112
#define W_ 112
#define HW_ 12544
#define F_ 128
#define OH_ 110
#define OW_ 110
#define NPOS 96800
#define KK_ 576
#define NWG 757           // ceil(NPOS/128)
#define OCTSTRIDE 802816  // B_*W_*H_*8 elems per c-oct plane
#define AELEMS 73728      // F_*KK_ fp16 elems = 144KB

__device__ __forceinline__ void gl_lds16(const void* g, void* l) {
  __builtin_amdgcn_global_load_lds((const __attribute__((address_space(1))) void*)g,
                                   (__attribute__((address_space(3))) void*)l,
                                   16, 0, 0);
}

// ---- prep: NCHW fp32 -> [c_oct][b][w][h]{8c} fp16 (B direct-load layout) ----
__global__ __launch_bounds__(256) void prep_inputT(const float* __restrict__ in,
                                                   u16* __restrict__ xT) {
  __shared__ float tile[8][8][113];  // [c][h][w], w-pad 1
  const int bid = blockIdx.x;        // 8 b x 8 oct x 14 h-stripes = 896
  const int b = bid / 112;
  const int r = bid % 112;
  const int oct = r / 14;
  const int hs = (r % 14) * 8;
  const int tid = threadIdx.x;

  for (int idx = tid; idx < 8 * 8 * 112; idx += 256) {
    int c = idx / 896;
    int rem = idx - c * 896;
    int h = rem / 112;
    int w = rem - h * 112;
    tile[c][h][w] = in[(((size_t)(b * 64 + oct * 8 + c)) * 112 + (hs + h)) * 112 + w];
  }
  __syncthreads();

  for (int idx = tid; idx < 896; idx += 256) {
    int w = idx >> 3;
    int h = idx & 7;
    f16x8 v;
#pragma unroll
    for (int c = 0; c < 8; ++c) v[c] = (_Float16)tile[c][h][w];
    size_t o = ((((size_t)oct * B_ + b) * W_ + w) * H_ + (hs + h)) * 8;
    *(f16x8*)(xT + o) = v;
  }
}

// ---- prep: kernel fp32 [f][KK] -> fragment-order A'[ko][f][8c] fp16 ----
// Conv A-read: quarter-wave = 16 consecutive f at one ko -> 256B contiguous (LDS-conflict-free).
__global__ __launch_bounds__(256) void prep_kerT(const float* __restrict__ k,
                                                 u16* __restrict__ kT) {
  int idx = blockIdx.x * 256 + threadIdx.x;
  if (idx < AELEMS) {
    int ko = idx >> 10;  // /(128*8)
    int rem = idx & 1023;
    int f = rem >> 3;
    int c = rem & 7;
    _Float16 h = (_Float16)k[f * KK_ + ko * 8 + c];
    kT[idx] = __builtin_bit_cast(u16, h);
  }
}

// ---------------- main: whole-A-in-LDS (144KB), ONE barrier, barrier-free K-loop ----------------
// A' (128x576 fp16 = 144KB) staged once via linear gl_lds (9216x16B). After one
// __syncthreads, 18 fully-unrolled steps of {4 B dwordx4 from L2 + 4 ds_read_b128 +
// 16 MFMA} with NO barriers -> compiler software-pipelines B loads (512-VGPR budget,
// 1 wave/SIMD). Frag reads are 256B contiguous per quarter-wave: conflict-free, no swizzle.
__global__ __launch_bounds__(256, 1) void conv_mfma(
    const u16* __restrict__ xT, const u16* __restrict__ kT,
    float* __restrict__ out) {
  __shared__ u16 lds[AELEMS];  // 144KB <= 160KB pool; 1 block/CU

  const int tid = threadIdx.x;
  const int wave = tid >> 6;
  const int lane = tid & 63;

  // bijective XCD-aware block swizzle (m204 form; NWG=757: q=94, r=5)
  const int orig = blockIdx.x;
  const int xcd = orig & 7;
  const int sub = orig >> 3;
  const int wg = (xcd < 5 ? xcd * 95 : 475 + (xcd - 5) * 94) + sub;
  const int n0 = wg * 128;

  const int l15 = lane & 15;
  const int l4 = lane >> 4;
  const int wr = wave >> 1;
  const int wc = wave & 1;

  // ---- B addressing: per-lane position offsets (elems), one per ni
  int posOff[4];
#pragma unroll
  for (int ni = 0; ni < 4; ++ni) {
    int n = n0 + wc * 64 + ni * 16 + l15;
    if (n >= NPOS) n = 0;
    int b = n / (OW_ * OH_);
    int r = n - b * (OW_ * OH_);
    int w = r / OH_;
    int h = r - w * OH_;
    posOff[ni] = ((b * W_ + w) * H_ + h) * 8;
  }
  const int l4Off = l4 * OCTSTRIDE;

  // ---- step-0 B loads issued BEFORE the stage barrier (independent of LDS)
  f16x8 b0[4];
#pragma unroll
  for (int ni = 0; ni < 4; ++ni) b0[ni] = *(const f16x8*)(xT + posOff[ni] + l4Off);

  // ---- stage ALL of A' into LDS: linear, 36 x 16B per thread
#pragma unroll
  for (int it = 0; it < 36; ++it) {
    const u32 off = (u32)((it * 256 + tid) * 16);
    gl_lds16((const char*)kT + off, (char*)lds + off);
  }
  __syncthreads();  // the ONLY barrier

  f32x4 acc[4][4] = {};

#pragma unroll
  for (int s = 0; s < 18; ++s) {
    const int tap = s >> 1;
    const int half = s & 1;
    const int i = tap / 3;      // W offset
    const int j = tap - i * 3;  // H offset
    const int sShift = (i * H_ + j) * 8 + half * 4 * OCTSTRIDE;

    // B: 4 per-lane 16B loads from L2 (hoistable arbitrarily early; no barriers)
    f16x8 bh[4];
    if (s == 0) {
#pragma unroll
      for (int ni = 0; ni < 4; ++ni) bh[ni] = b0[ni];
    } else {
#pragma unroll
      for (int ni = 0; ni < 4; ++ni)
        bh[ni] = *(const f16x8*)(xT + posOff[ni] + l4Off + sShift);
    }

    // A: 4 ds_read_b128, fragment-order (256B contiguous per quarter-wave)
    f16x8 ah[4];
    const int aBase = ((s * 4 + l4) * 128 + wr * 64 + l15) * 8;
#pragma unroll
    for (int mi = 0; mi < 4; ++mi) ah[mi] = *(const f16x8*)&lds[aBase + mi * 128];

#pragma unroll
    for (int mi = 0; mi < 4; ++mi)
#pragma unroll
      for (int ni = 0; ni < 4; ++ni)
        acc[mi][ni] = __builtin_amdgcn_mfma_f32_16x16x32_f16(ah[mi], bh[ni], acc[mi][ni], 0, 0, 0);
  }

  // epilogue: D col = lane&15 -> n, row = (lane>>4)*4+q -> f
#pragma unroll
  for (int ni = 0; ni < 4; ++ni) {
    int n = n0 + wc * 64 + ni * 16 + l15;
    if (n >= NPOS) continue;
    int b = n / (OW_ * OH_);
    int r = n - b * (OW_ * OH_);
    int w = r / OH_;
    int h = r - w * OH_;
    float* op = out + ((size_t)(b * F_) * OW_ + w) * OH_ + h;
#pragma unroll
    for (int mi = 0; mi < 4; ++mi) {
      int fbase = wr * 64 + mi * 16 + l4 * 4;
#pragma unroll
      for (int qq = 0; qq < 4; ++qq) {
        op[(size_t)(fbase + qq) * (OW_ * OH_)] = acc[mi][ni][qq];
      }
    }
  }
}

// ---------------- correctness fallback (ws too small) ----------------
__global__ void naive_conv(const float* __restrict__ in, const float* __restrict__ ker,
                           float* __restrict__ out) {
  int idx = blockIdx.x * 256 + threadIdx.x;
  const int total = B_ * F_ * OW_ * OH_;
  if (idx >= total) return;
  int h = idx % OH_;
  int w = (idx / OH_) % OW_;
  int f = (idx / (OW_ * OH_)) % F_;
  int b = idx / (F_ * OW_ * OH_);
  float s = 0.f;
  for (int tap = 0; tap < 9; ++tap) {
    int i = tap / 3, j = tap % 3;
    const float* ip = in + ((size_t)b * C_ * H_ + (h + j)) * W_ + (w + i);
    const float* kp = ker + (size_t)f * KK_ + tap * C_;
    for (int c = 0; c < C_; ++c) s += ip[(size_t)c * HW_] * kp[c];
  }
  out[idx] = s;
}

extern "C" void kernel_launch(void* const* d_in, const int* in_sizes, int n_in,
                              void* d_out, int out_size, void* d_ws, size_t ws_size,
                              hipStream_t stream) {
  const float* in = (const float*)d_in[0];
  const float* ker = (const float*)d_in[1];
  float* out = (float*)d_out;

  const size_t xElems = (size_t)B_ * H_ * W_ * C_;  // 6,422,528
  const size_t need = (xElems + AELEMS) * 2;        // ~13 MB fp16

  if (ws_size < need) {
    int total = B_ * F_ * OW_ * OH_;
    naive_conv<<<(total + 255) / 256, 256, 0, stream>>>(in, ker, out);
    return;
  }

  u16* xT = (u16*)d_ws;
  u16* kT = xT + xElems;

  prep_inputT<<<896, 256, 0, stream>>>(in, xT);
  prep_kerT<<<(int)((AELEMS + 255) / 256), 256, 0, stream>>>(ker, kT);
  conv_mfma<<<NWG, 256, 0, stream>>>(xT, kT, out);
}

// Round 9
// 43.325 us; speedup vs baseline: 1.0729x; 1.0729x over previous
//
#include <hip/hip_runtime.h>

typedef unsigned short u16;
typedef unsigned int u32;
typedef _Float16 f16x8 __attribute__((ext_vector_type(8)));
typedef float f32x4 __attribute__((ext_vector_type(4)));

#define B_ 8
#define C_ 64
#define H_ 112
#define W_ 112
#define HW_ 12544
#define F_ 128
#define OH_ 110
#define OW_ 110
#define OWOH 12100
#define NPOS 96800
#define KK_ 576
#define NT_ 384           // output positions per block
#define NWG2 253          // ceil(NPOS/NT_) <= 256 CUs: single dispatch round
#define OCTSTRIDE 802816  // B_*W_*H_*8 elems per c-oct plane
#define AELEMS 73728      // F_*KK_ fp16 elems = 144KB

__device__ __forceinline__ void gl_lds16(const void* g, void* l) {
  __builtin_amdgcn_global_load_lds((const __attribute__((address_space(1))) void*)g,
                                   (__attribute__((address_space(3))) void*)l,
                                   16, 0, 0);
}

// ---- fused prep: blocks 0..895 transpose input; blocks 896..931 convert kernel ----
// input: NCHW fp32 -> [c_oct][b][w][h]{8c} fp16 ; kernel: [f][KK] fp32 -> A'[ko][f][8c] fp16
__global__ __launch_bounds__(256) void prep_all(const float* __restrict__ in,
                                                const float* __restrict__ k,
                                                u16* __restrict__ xT,
                                                u16* __restrict__ kT) {
  const int bid = blockIdx.x;
  const int tid = threadIdx.x;
  if (bid >= 896) {  // kernel conversion: 36 blocks x 2048 elems
    const int base = (bid - 896) * 2048;
#pragma unroll
    for (int t = 0; t < 8; ++t) {
      int idx = base + t * 256 + tid;
      int ko = idx >> 10;  // /(128*8)
      int rem = idx & 1023;
      int f = rem >> 3;
      int c = rem & 7;
      _Float16 h = (_Float16)k[f * KK_ + ko * 8 + c];
      kT[idx] = __builtin_bit_cast(u16, h);
    }
    return;
  }
  __shared__ float tile[8][8][113];  // [c][h][w], w-pad 1
  const int b = bid / 112;
  const int r = bid % 112;
  const int oct = r / 14;
  const int hs = (r % 14) * 8;

  for (int idx = tid; idx < 8 * 8 * 112; idx += 256) {
    int c = idx / 896;
    int rem = idx - c * 896;
    int h = rem / 112;
    int w = rem - h * 112;
    tile[c][h][w] = in[(((size_t)(b * 64 + oct * 8 + c)) * 112 + (hs + h)) * 112 + w];
  }
  __syncthreads();

  for (int idx = tid; idx < 896; idx += 256) {
    int w = idx >> 3;
    int h = idx & 7;
    f16x8 v;
#pragma unroll
    for (int c = 0; c < 8; ++c) v[c] = (_Float16)tile[c][h][w];
    size_t o = ((((size_t)oct * B_ + b) * W_ + w) * H_ + (hs + h)) * 8;
    *(f16x8*)(xT + o) = v;
  }
}

// ---------------- main: 128f x 384n tile, whole-A in LDS (144KB), single round ----------------
// 253 blocks <= 256 CUs: one dispatch round, A staged ONCE per CU total. One barrier.
// Per wave per K=32 step: 8 ds_read_b128 + 6 B dwordx4 feed 48 MFMAs (~990 SIMD-cyc)
// -> single-wave ILP covers all load latency; no barriers in the K-loop.
// Frag reads 256B contiguous per quarter-wave: LDS conflict-free (0 in r3-r6).
__global__ __launch_bounds__(256, 1) void conv_mfma(
    const u16* __restrict__ xT, const u16* __restrict__ kT,
    float* __restrict__ out) {
  __shared__ u16 lds[AELEMS];  // 144KB; 1 block/CU

  const int tid = threadIdx.x;
  const int wave = tid >> 6;
  const int lane = tid & 63;

  // bijective XCD-aware block swizzle (m204 form; NWG2=253: q=31, r=5)
  const int orig = blockIdx.x;
  const int xcd = orig & 7;
  const int sub = orig >> 3;
  const int wg = (xcd < 5 ? xcd * 32 : 160 + (xcd - 5) * 31) + sub;
  const int n0 = wg * NT_ + wave * 96;  // this wave's 96-position slice

  const int l15 = lane & 15;
  const int l4 = lane >> 4;

  // ---- B addressing: per-lane position offsets (elems), one per ni (6 x 16 = 96 n)
  int posOff[6];
#pragma unroll
  for (int ni = 0; ni < 6; ++ni) {
    int n = n0 + ni * 16 + l15;
    if (n >= NPOS) n = 0;
    int b = n / OWOH;
    int r = n - b * OWOH;
    int w = r / OH_;
    int h = r - w * OH_;
    posOff[ni] = ((b * W_ + w) * H_ + h) * 8;
  }
  const int l4Off = l4 * OCTSTRIDE;

  // ---- step-0 B loads issued BEFORE the stage barrier
  f16x8 b0[6];
#pragma unroll
  for (int ni = 0; ni < 6; ++ni) b0[ni] = *(const f16x8*)(xT + posOff[ni] + l4Off);

  // ---- stage ALL of A' into LDS: linear, 36 x 16B per thread
#pragma unroll
  for (int it = 0; it < 36; ++it) {
    const u32 off = (u32)((it * 256 + tid) * 16);
    gl_lds16((const char*)kT + off, (char*)lds + off);
  }
  __syncthreads();  // the ONLY barrier

  f32x4 acc[8][6] = {};

#pragma unroll
  for (int s = 0; s < 18; ++s) {
    const int tap = s >> 1;
    const int half = s & 1;
    const int i = tap / 3;      // W offset
    const int j = tap - i * 3;  // H offset
    const int sShift = (i * H_ + j) * 8 + half * 4 * OCTSTRIDE;

    // B: 6 per-lane 16B loads from L2 (no barriers -> freely schedulable)
    f16x8 bh[6];
    if (s == 0) {
#pragma unroll
      for (int ni = 0; ni < 6; ++ni) bh[ni] = b0[ni];
    } else {
#pragma unroll
      for (int ni = 0; ni < 6; ++ni)
        bh[ni] = *(const f16x8*)(xT + posOff[ni] + l4Off + sShift);
    }

    // A: 8 ds_read_b128, fragment-order (256B contiguous per quarter-wave)
    f16x8 ah[8];
    const int aBase = ((s * 4 + l4) * 128 + l15) * 8;
#pragma unroll
    for (int mi = 0; mi < 8; ++mi) ah[mi] = *(const f16x8*)&lds[aBase + mi * 128];

#pragma unroll
    for (int mi = 0; mi < 8; ++mi)
#pragma unroll
      for (int ni = 0; ni < 6; ++ni)
        acc[mi][ni] = __builtin_amdgcn_mfma_f32_16x16x32_f16(ah[mi], bh[ni], acc[mi][ni], 0, 0, 0);
  }

  // epilogue: D col = l15 -> n, row = l4*4+q (within mi*16 f-block) -> f
#pragma unroll
  for (int ni = 0; ni < 6; ++ni) {
    int n = n0 + ni * 16 + l15;
    if (n >= NPOS) continue;
    int b = n / OWOH;
    int r = n - b * OWOH;
    int w = r / OH_;
    int h = r - w * OH_;
    float* op = out + ((size_t)(b * F_) * OW_ + w) * OH_ + h;
#pragma unroll
    for (int mi = 0; mi < 8; ++mi) {
      int fbase = mi * 16 + l4 * 4;
#pragma unroll
      for (int qq = 0; qq < 4; ++qq) {
        op[(size_t)(fbase + qq) * OWOH] = acc[mi][ni][qq];
      }
    }
  }
}

// ---------------- correctness fallback (ws too small) ----------------
__global__ void naive_conv(const float* __restrict__ in, const float* __restrict__ ker,
                           float* __restrict__ out) {
  int idx = blockIdx.x * 256 + threadIdx.x;
  const int total = B_ * F_ * OW_ * OH_;
  if (idx >= total) return;
  int h = idx % OH_;
  int w = (idx / OH_) % OW_;
  int f = (idx / (OW_ * OH_)) % F_;
  int b = idx / (F_ * OW_ * OH_);
  float s = 0.f;
  for (int tap = 0; tap < 9; ++tap) {
    int i = tap / 3, j = tap % 3;
    const float* ip = in + ((size_t)b * C_ * H_ + (h + j)) * W_ + (w + i);
    const float* kp = ker + (size_t)f * KK_ + tap * C_;
    for (int c = 0; c < C_; ++c) s += ip[(size_t)c * HW_] * kp[c];
  }
  out[idx] = s;
}

extern "C" void kernel_launch(void* const* d_in, const int* in_sizes, int n_in,
                              void* d_out, int out_size, void* d_ws, size_t ws_size,
                              hipStream_t stream) {
  const float* in = (const float*)d_in[0];
  const float* ker = (const float*)d_in[1];
  float* out = (float*)d_out;

  const size_t xElems = (size_t)B_ * H_ * W_ * C_;  // 6,422,528
  const size_t need = (xElems + AELEMS) * 2;        // ~13 MB fp16

  if (ws_size < need) {
    int total = B_ * F_ * OW_ * OH_;
    naive_conv<<<(total + 255) / 256, 256, 0, stream>>>(in, ker, out);
    return;
  }

  u16* xT = (u16*)d_ws;
  u16* kT = xT + xElems;

  prep_all<<<932, 256, 0, stream>>>(in, ker, xT, kT);
  conv_mfma<<<NWG2, 256, 0, stream>>>(xT, kT, out);
}

// Round 10
// 37.260 us; speedup vs baseline: 1.2476x; 1.1628x over previous
//
#include <hip/hip_runtime.h>

typedef unsigned short u16;
typedef unsigned int u32;
typedef _Float16 f16x8 __attribute__((ext_vector_type(8)));
typedef float f32x4 __attribute__((ext_vector_type(4)));

#define B_ 8
#define C_ 64
#define H_ 112
#define W_ 112
#define HW_ 12544
#define F_ 128
#define OH_ 110
#define OW_ 110
#define OWOH 12100
#define NPOS 96800
#define KK_ 576
#define NT_ 384           // output positions per block
#define NWGF 506          // 253 n-blocks x 2 f-halves <= 512: one dispatch round, 2 blocks/CU
#define OCTSTRIDE 802816  // B_*W_*H_*8 elems per c-oct plane
#define AELEMS 73728      // F_*KK_ fp16 elems (kT total)
#define AHALF 36864       // 64f x 576k fp16 elems = 72KB LDS per block

__device__ __forceinline__ void gl_lds16(const void* g, void* l) {
  __builtin_amdgcn_global_load_lds((const __attribute__((address_space(1))) void*)g,
                                   (__attribute__((address_space(3))) void*)l,
                                   16, 0, 0);
}

// ---- fused prep: blocks 0..895 transpose input; blocks 896..931 convert kernel ----
// input: NCHW fp32 -> [c_oct][b][w][h]{8c} fp16 ; kernel: [f][KK] fp32 -> A'[ko][f][8c] fp16
__global__ __launch_bounds__(256) void prep_all(const float* __restrict__ in,
                                                const float* __restrict__ k,
                                                u16* __restrict__ xT,
                                                u16* __restrict__ kT) {
  const int bid = blockIdx.x;
  const int tid = threadIdx.x;
  if (bid >= 896) {  // kernel conversion: 36 blocks x 2048 elems
    const int base = (bid - 896) * 2048;
#pragma unroll
    for (int t = 0; t < 8; ++t) {
      int idx = base + t * 256 + tid;
      int ko = idx >> 10;  // /(128*8)
      int rem = idx & 1023;
      int f = rem >> 3;
      int c = rem & 7;
      _Float16 h = (_Float16)k[f * KK_ + ko * 8 + c];
      kT[idx] = __builtin_bit_cast(u16, h);
    }
    return;
  }
  __shared__ float tile[8][8][113];  // [c][h][w], w-pad 1
  const int b = bid / 112;
  const int r = bid % 112;
  const int oct = r / 14;
  const int hs = (r % 14) * 8;

  for (int idx = tid; idx < 8 * 8 * 112; idx += 256) {
    int c = idx / 896;
    int rem = idx - c * 896;
    int h = rem / 112;
    int w = rem - h * 112;
    tile[c][h][w] = in[(((size_t)(b * 64 + oct * 8 + c)) * 112 + (hs + h)) * 112 + w];
  }
  __syncthreads();

  for (int idx = tid; idx < 896; idx += 256) {
    int w = idx >> 3;
    int h = idx & 7;
    f16x8 v;
#pragma unroll
    for (int c = 0; c < 8; ++c) v[c] = (_Float16)tile[c][h][w];
    size_t o = ((((size_t)oct * B_ + b) * W_ + w) * H_ + (hs + h)) * 8;
    *(f16x8*)(xT + o) = v;
  }
}

// ---------------- main: 64f x 384n per block, A-half in 72KB LDS, 2 blocks/CU ----------------
// 506 blocks <= 512 (one round). 2 waves/SIMD: TLP covers load stalls (m114) in the
// barrier-free K-loop. Per wave per K=32 step: 4 ds_read_b128 + 6 B dwordx4 + 24 MFMA.
// Paired f-halves of the same n-block land on the same XCD (B shared in L2).
// Frag reads 256B contiguous per quarter-wave: LDS conflict-free.
__global__ __launch_bounds__(256, 2) void conv_mfma(
    const u16* __restrict__ xT, const u16* __restrict__ kT,
    float* __restrict__ out) {
  __shared__ u16 lds[AHALF];  // [ko:72][64f][8c] = 72KB; 2 blocks/CU

  const int tid = threadIdx.x;
  const int wave = tid >> 6;
  const int lane = tid & 63;

  // bijective XCD swizzle for 506 (q=63, r=2): xcd 0,1 get 64 wgs; 2..7 get 63.
  // Consecutive wg (= f-half pair of one n-block) stay on one XCD.
  const int orig = blockIdx.x;
  const int xcd = orig & 7;
  const int sub = orig >> 3;
  const int wg = (xcd < 2 ? xcd * 64 : 128 + (xcd - 2) * 63) + sub;
  const int nblk = wg >> 1;
  const int fh = wg & 1;  // which 64-filter half
  const int n0 = nblk * NT_ + wave * 96;

  const int l15 = lane & 15;
  const int l4 = lane >> 4;

  // ---- B addressing: per-lane position offsets (elems), 6 x 16 = 96 n per wave
  int posOff[6];
#pragma unroll
  for (int ni = 0; ni < 6; ++ni) {
    int n = n0 + ni * 16 + l15;
    if (n >= NPOS) n = 0;
    int b = n / OWOH;
    int r = n - b * OWOH;
    int w = r / OH_;
    int h = r - w * OH_;
    posOff[ni] = ((b * W_ + w) * H_ + h) * 8;
  }
  const int l4Off = l4 * OCTSTRIDE;

  // ---- step-0 B loads issued BEFORE the stage barrier
  f16x8 b0[6];
#pragma unroll
  for (int ni = 0; ni < 6; ++ni) b0[ni] = *(const f16x8*)(xT + posOff[ni] + l4Off);

  // ---- stage this block's A-half into LDS: 18 x 16B per thread.
  // LDS chunk m (16B units) = ko*64 + f_local  ->  src elems: ko*1024 + fh*512 + f_local*8
#pragma unroll
  for (int it = 0; it < 18; ++it) {
    const int m = it * 256 + tid;
    const int src = ((m >> 6) << 10) + (fh << 9) + ((m & 63) << 3);
    gl_lds16(kT + src, (char*)lds + m * 16);
  }
  __syncthreads();  // the ONLY barrier

  f32x4 acc[4][6] = {};

#pragma unroll
  for (int s = 0; s < 18; ++s) {
    const int tap = s >> 1;
    const int half = s & 1;
    const int i = tap / 3;      // W offset
    const int j = tap - i * 3;  // H offset
    const int sShift = (i * H_ + j) * 8 + half * 4 * OCTSTRIDE;

    // B: 6 per-lane 16B loads from L2 (no barriers -> freely schedulable)
    f16x8 bh[6];
    if (s == 0) {
#pragma unroll
      for (int ni = 0; ni < 6; ++ni) bh[ni] = b0[ni];
    } else {
#pragma unroll
      for (int ni = 0; ni < 6; ++ni)
        bh[ni] = *(const f16x8*)(xT + posOff[ni] + l4Off + sShift);
    }

    // A: 4 ds_read_b128, fragment-order (256B contiguous per quarter-wave)
    f16x8 ah[4];
    const int ko = s * 4 + l4;  // 0..71
    const int aBase = ((ko << 6) + l15) * 8;
#pragma unroll
    for (int mi = 0; mi < 4; ++mi) ah[mi] = *(const f16x8*)&lds[aBase + mi * 128];

#pragma unroll
    for (int mi = 0; mi < 4; ++mi)
#pragma unroll
      for (int ni = 0; ni < 6; ++ni)
        acc[mi][ni] = __builtin_amdgcn_mfma_f32_16x16x32_f16(ah[mi], bh[ni], acc[mi][ni], 0, 0, 0);
  }

  // epilogue: D col = l15 -> n, row = l4*4+qq within (fh*64 + mi*16) f-block
#pragma unroll
  for (int ni = 0; ni < 6; ++ni) {
    int n = n0 + ni * 16 + l15;
    if (n >= NPOS) continue;
    int b = n / OWOH;
    int r = n - b * OWOH;
    int w = r / OH_;
    int h = r - w * OH_;
    float* op = out + ((size_t)(b * F_) * OW_ + w) * OH_ + h;
#pragma unroll
    for (int mi = 0; mi < 4; ++mi) {
      int fbase = fh * 64 + mi * 16 + l4 * 4;
#pragma unroll
      for (int qq = 0; qq < 4; ++qq) {
        op[(size_t)(fbase + qq) * OWOH] = acc[mi][ni][qq];
      }
    }
  }
}

// ---------------- correctness fallback (ws too small) ----------------
__global__ void naive_conv(const float* __restrict__ in, const float* __restrict__ ker,
                           float* __restrict__ out) {
  int idx = blockIdx.x * 256 + threadIdx.x;
  const int total = B_ * F_ * OW_ * OH_;
  if (idx >= total) return;
  int h = idx % OH_;
  int w = (idx / OH_) % OW_;
  int f = (idx / (OW_ * OH_)) % F_;
  int b = idx / (F_ * OW_ * OH_);
  float s = 0.f;
  for (int tap = 0; tap < 9; ++tap) {
    int i = tap / 3, j = tap % 3;
    const float* ip = in + ((size_t)b * C_ * H_ + (h + j)) * W_ + (w + i);
    const float* kp = ker + (size_t)f * KK_ + tap * C_;
    for (int c = 0; c < C_; ++c) s += ip[(size_t)c * HW_] * kp[c];
  }
  out[idx] = s;
}

extern "C" void kernel_launch(void* const* d_in, const int* in_sizes, int n_in,
                              void* d_out, int out_size, void* d_ws, size_t ws_size,
                              hipStream_t stream) {
  const float* in = (const float*)d_in[0];
  const float* ker = (const float*)d_in[1];
  float* out = (float*)d_out;

  const size_t xElems = (size_t)B_ * H_ * W_ * C_;  // 6,422,528
  const size_t need = (xElems + AELEMS) * 2;        // ~13 MB fp16

  if (ws_size < need) {
    int total = B_ * F_ * OW_ * OH_;
    naive_conv<<<(total + 255) / 256, 256, 0, stream>>>(in, ker, out);
    return;
  }

  u16* xT = (u16*)d_ws;
  u16* kT = xT + xElems;

  prep_all<<<932, 256, 0, stream>>>(in, ker, xT, kT);
  conv_mfma<<<NWGF, 256, 0, stream>>>(xT, kT, out);
}